// Round 10
// baseline (349.114 us; speedup 1.0000x reference)
//
#include <hip/hip_runtime.h>
#include <hip/hip_bf16.h>
#include <stdint.h>

#define CCH 256

typedef __attribute__((ext_vector_type(8))) short short8;
typedef __attribute__((ext_vector_type(4))) float f32x4;

__device__ __forceinline__ float lrelu(float v) { return v > 0.f ? v : 0.1f * v; }

__device__ __forceinline__ unsigned short f2bf(float f) {
    __hip_bfloat16 h = __float2bfloat16(f);
    return *reinterpret_cast<unsigned short*>(&h);
}

// async global->LDS, 16B per lane; global addr per-lane, LDS dst wave-uniform (+lane*16)
__device__ __forceinline__ void gl_lds16(const void* g, void* s) {
    __builtin_amdgcn_global_load_lds(
        (const __attribute__((address_space(1))) unsigned int*)(uintptr_t)g,
        (__attribute__((address_space(3))) unsigned int*)(unsigned int)(uintptr_t)s,
        16, 0, 0);
}

// compiler memory fence + hw barrier + fence: raw s_barrier that LDS ops can't cross
__device__ __forceinline__ void pipe_barrier() {
    asm volatile("" ::: "memory");
    __builtin_amdgcn_s_barrier();
    asm volatile("" ::: "memory");
}

// Fused preprocessing. z < 16: NCHW fp32 -> channel-chunked bf16 out[b][kc][y*64+x][32ci]
// (z = b). z == 16: aux work — flat = bx + 8*by; flat<144: weight transform
// (which = flat/72, ss = flat%72) into FRAGMENT-MAJOR wt[ss][f=0..15][l=0..63][8]
// (lane l of frag f: co = f*16+(l&15), ci = kc*32+(l>>4)*8+u); flat in [144,160): zero pool.
// grid (8, 64, 17), block 256.
__global__ __launch_bounds__(256)
void pre_k(const float* __restrict__ in, unsigned short* __restrict__ out,
           const float* __restrict__ w1, const float* __restrict__ w2,
           unsigned short* __restrict__ o1, unsigned short* __restrict__ o2,
           float* __restrict__ pool)
{
    __shared__ float t[32][65];
    const int tid = threadIdx.x;
    if (blockIdx.z == 16) {
        const int flat = blockIdx.x + 8 * blockIdx.y;      // 0..511
        if (flat < 144) {
            const int which = flat / 72, ss = flat - which * 72;
            const int kc = ss / 9, tt = ss - kc * 9;
            const float* w = which ? w2 : w1;
            unsigned short* o = which ? o2 : o1;
#pragma unroll
            for (int rep = 0; rep < 4; ++rep) {
                int slot = tid + rep * 256;                // (frag f, lane l)
                int f = slot >> 6, l = slot & 63;
                int co = f * 16 + (l & 15);
                int q  = l >> 4;
                union { unsigned short us[8]; uint4 v; } u;
#pragma unroll
                for (int uu = 0; uu < 8; ++uu)
                    u.us[uu] = f2bf(w[((size_t)co * 256 + kc * 32 + q * 8 + uu) * 9 + tt]);
                *(uint4*)(o + (size_t)ss * 8192 + slot * 8) = u.v;
            }
        } else if (flat < 160) {
            pool[(flat - 144) * 256 + tid] = 0.f;
        }
        return;
    }
    const int kc = blockIdx.x, y = blockIdx.y, b = blockIdx.z;
    const float* src = in + ((size_t)(b * 256 + kc * 32)) * 4096 + y * 64;
#pragma unroll
    for (int i = 0; i < 2; ++i) {
        int idx = tid + i * 256;            // 0..511
        int cl = idx >> 4, xg = idx & 15;
        float4 v = *(const float4*)(src + (size_t)cl * 4096 + xg * 4);
        t[cl][xg * 4 + 0] = v.x; t[cl][xg * 4 + 1] = v.y;
        t[cl][xg * 4 + 2] = v.z; t[cl][xg * 4 + 3] = v.w;
    }
    __syncthreads();
    const int x = tid >> 2, cg = tid & 3;
    union { unsigned short us[8]; uint4 v; } u;
#pragma unroll
    for (int j = 0; j < 8; ++j) u.us[j] = f2bf(t[cg * 8 + j][x]);
    unsigned short* dst = out + (((size_t)(b * 8 + kc) * 4096 + y * 64 + x) * 32 + cg * 8);
    *(uint4*)dst = u.v;
}

// Implicit-GEMM 3x3 VALID conv, bf16 MFMA 16x16x32 (R5 skeleton).
// M=Cout=256, N=pixels (block 128), K = 72 stages (kc,tap) x 32.
// Block tile 256x128, 4 waves 2x2, wave tile 128x64: a[8] x b[4], acc 8x4 f32x4.
// 2 blocks/CU. 5 schedule variants all measured additive (MFMA + LDS cycles), so
// this round CUTS LDS TRAFFIC: B goes global -> REGISTERS directly (the gl_lds16
// per-lane global address IS the per-lane fragment address, so global_load_dwordx4
// delivers the identical bytes to the identical lanes). LDS/block-stage 72 -> 48 KB
// (A-write 16 + A-read 32). B regs double-buffered (named rb0/rb1, 2-unrolled
// parity). Per-wave VMEM/stage = 4 A-DMA + 4 B-loads; vmcnt(8) retires the
// previous iteration's 8 ops (fences keep iterations ordered), keeping the current
// iteration's 8 in flight across the barrier. wn-sharing wave pairs load the same
// B lines -> L1 hits; no 256-CU shared-line hotspot (unlike R6's A-direct).
// im: [b][kc][WIN*WIN][32] bf16; wt: [ss][16][64][8] bf16 (fragment-major).
// POOL=0: h1 out [b][kc'][NVAL][32] (bias+lrelu, bf16). POOL=1: sum -> atomicAdd pool.
// grid (ceil(NVAL/128), 16 b), block 256, 2 blocks/CU (LDS 49152 B).
template<int POOL, int WIN, int WOUT>
__global__ __launch_bounds__(256, 2)
void convmm_k(const unsigned short* __restrict__ im, const unsigned short* __restrict__ wt,
              const float* __restrict__ bias, unsigned short* __restrict__ outp,
              float* __restrict__ pool)
{
    constexpr int HINPIX = WIN * WIN;
    constexpr int NVAL   = WOUT * WOUT;
    constexpr int NB = 16 * 512;               // A-only buffer: 16 frags x 1KB = 16KB
    __shared__ __align__(16) short Ls[3 * NB]; // 49152 B

    const int tid  = threadIdx.x;
    const int wave = tid >> 6;
    const int lane = tid & 63;
    const int quad = lane >> 4;
    const int l15  = lane & 15;
    const int wm   = (wave & 1) * 128;     // m offset of wave tile (co)
    const int wn   = (wave >> 1) * 64;     // n offset of wave tile (px)
    const int nb0  = blockIdx.x * 128;
    const int b    = blockIdx.y;

    // A staging: wave stages frags 4w..4w+3 (1KB each, linear src+dst)
    const unsigned short* abase = wt + (size_t)(wave * 4) * 512 + (size_t)lane * 8;
    // B direct: lane l of frag j holds px = wn + j*16 + l15, k-chunk quad.
    size_t bofsR[4];
#pragma unroll
    for (int j = 0; j < 4; ++j) {
        int nn = nb0 + wn + j * 16 + l15;
        if (nn > NVAL - 1) nn = NVAL - 1;
        int y = nn / WOUT, x = nn - y * WOUT;
        bofsR[j] = ((size_t)(b * 8) * HINPIX + (size_t)y * WIN + x) * 32 + quad * 8;
    }

    f32x4 acc[8][4];
#pragma unroll
    for (int i = 0; i < 8; ++i)
#pragma unroll
        for (int j = 0; j < 4; ++j) { f32x4 z = {0.f, 0.f, 0.f, 0.f}; acc[i][j] = z; }

    // issue one stage's 4 A gl_lds16 into LDS buffer `buf`
    auto stageA = [&](int ss, short* buf) {
        const size_t aoff = (size_t)ss * 8192;
#pragma unroll
        for (int h = 0; h < 4; ++h)
            gl_lds16(abase + aoff + h * 512, buf + (wave * 4 + h) * 512);
    };

    // load stage ss's 4 B frags straight into registers (4 x global_load_dwordx4)
    auto loadB = [&](int ss, short8 (&rb)[4]) {
        const int kc = ss / 9, t = ss - kc * 9;
        const int ky = t / 3, kx = t - ky * 3;
        const size_t boff = ((size_t)kc * HINPIX + (size_t)ky * WIN + kx) * 32;
#pragma unroll
        for (int j = 0; j < 4; ++j)
            rb[j] = *(const short8*)(im + bofsR[j] + boff);
    };

    // consume: 8 ds_read_b128 (A frags, 1KB-linear per wave) + 32 MFMA with reg B
    auto compute = [&](const short* buf, const short8 (&rb)[4]) {
        const short* ap = buf + (size_t)(wave & 1) * 8 * 512 + lane * 8;
        short8 a[8];
#pragma unroll
        for (int i = 0; i < 8; ++i)
            a[i] = *(const short8*)(ap + i * 512);
        __builtin_amdgcn_s_setprio(1);
#pragma unroll
        for (int i = 0; i < 8; ++i)
#pragma unroll
            for (int j = 0; j < 4; ++j)
                acc[i][j] = __builtin_amdgcn_mfma_f32_16x16x32_bf16(a[i], rb[j], acc[i][j], 0, 0, 0);
        __builtin_amdgcn_s_setprio(0);
    };

    short* c0 = Ls;
    short* c1 = Ls + NB;
    short* c2 = Ls + 2 * NB;
    short8 rb0[4], rb1[4];

    // prologue: B(0)->rb0, A(0)->c0, A(1)->c1, B(1)->rb1 (16 VMEM ops).
    // vmcnt(8) retires the oldest 8 (B(0)+A(0)); A(1)+B(1) stay in flight.
    loadB(0, rb0);
    stageA(0, c0);
    stageA(1, c1);
    loadB(1, rb1);
    asm volatile("s_waitcnt vmcnt(8)" ::: "memory");
    pipe_barrier();

    // invariant at top of even iter s: c0 = A(s) resident, rb0 = B(s) ready,
    // in flight: A(s+1) (4, into c1) + B(s+1) (4, into rb1).
    for (int s = 0; s < 70; s += 2) {
        // even: compute s (A from c0, B from rb0); prefetch A(s+2), B(s+2)->rb0
        stageA(s + 2, c2);
        compute(c0, rb0);
        loadB(s + 2, rb0);                                 // after MFMAs read rb0
        asm volatile("s_waitcnt vmcnt(8)" ::: "memory");   // retire A(s+1)+B(s+1)
        pipe_barrier();
        { short* t = c0; c0 = c1; c1 = c2; c2 = t; }
        // odd: compute s+1 (A from c0, B from rb1); prefetch A(s+3), B(s+3)->rb1
        stageA(s + 3, c2);
        compute(c0, rb1);
        loadB(s + 3, rb1);
        asm volatile("s_waitcnt vmcnt(8)" ::: "memory");   // retire A(s+2)+B(s+2)
        pipe_barrier();
        { short* t = c0; c0 = c1; c1 = c2; c2 = t; }
    }
    // tail: c0 = A(70), rb0 = B(70) ready; A(71)+B(71) in flight
    compute(c0, rb0);                                      // stage 70
    asm volatile("s_waitcnt vmcnt(0)" ::: "memory");
    pipe_barrier();
    compute(c1, rb1);                                      // stage 71

    // D layout: col(px)=l15, row(co)=quad*4+reg
    const int co_l = wm + quad * 4;
    if (!POOL) {
#pragma unroll
        for (int i = 0; i < 8; ++i) {
            const int c0i = co_l + i * 16;
            float4 bv = *(const float4*)(bias + c0i);
            unsigned short* dstp = outp + ((size_t)(b * 8 + (c0i >> 5)) * NVAL) * 32 + (c0i & 31);
#pragma unroll
            for (int j = 0; j < 4; ++j) {
                int nn = nb0 + wn + j * 16 + l15;
                if (nn < NVAL) {
                    ushort4 pk = make_ushort4(
                        f2bf(lrelu(acc[i][j].x + bv.x)),
                        f2bf(lrelu(acc[i][j].y + bv.y)),
                        f2bf(lrelu(acc[i][j].z + bv.z)),
                        f2bf(lrelu(acc[i][j].w + bv.w)));
                    *(ushort4*)(dstp + (size_t)nn * 32) = pk;
                }
            }
        }
    } else {
#pragma unroll
        for (int i = 0; i < 8; ++i) {
            const int c0i = co_l + i * 16;
            float4 bv = *(const float4*)(bias + c0i);
            float s0 = 0.f, s1 = 0.f, s2 = 0.f, s3 = 0.f;
#pragma unroll
            for (int j = 0; j < 4; ++j) {
                int nn = nb0 + wn + j * 16 + l15;
                if (nn < NVAL) {
                    s0 += lrelu(acc[i][j].x + bv.x);
                    s1 += lrelu(acc[i][j].y + bv.y);
                    s2 += lrelu(acc[i][j].z + bv.z);
                    s3 += lrelu(acc[i][j].w + bv.w);
                }
            }
#pragma unroll
            for (int off = 1; off < 16; off <<= 1) {
                s0 += __shfl_xor(s0, off, 64);
                s1 += __shfl_xor(s1, off, 64);
                s2 += __shfl_xor(s2, off, 64);
                s3 += __shfl_xor(s3, off, 64);
            }
            if (l15 == 0) {
                float* pp = pool + b * 256 + c0i;
                atomicAdd(pp + 0, s0); atomicAdd(pp + 1, s1);
                atomicAdd(pp + 2, s2); atomicAdd(pp + 3, s3);
            }
        }
    }
}

// Per-sample depthwise 3x3 SAME + bias, fp32, LDS-staged, with FUSED kernel-weight
// computation: k[q] = (1/3600)*sum_c pool[b][c']*w3[c*9+q][c'] + b3[c*9+q]
// (replaces the separate kern_gemm_k launch; w3 is L2-resident).
// One block (256 thr) per (b,c) plane. LDS tile 66 rows x 67 stride; halo-only zero.
__global__ __launch_bounds__(256)
void dw_k(const float* __restrict__ x, const float* __restrict__ pool,
          const float* __restrict__ w3, const float* __restrict__ b3,
          const float* __restrict__ bias, float* __restrict__ out)
{
    __shared__ float t[66 * 67];
    const int tid = threadIdx.x;
    const int bc = blockIdx.x;
    const int c = bc & (CCH - 1);
    const int b = bc >> 8;
    const int lane = tid & 63, wv = tid >> 6;

    // fused kern: 9 dot products of w3 rows (c*9..c*9+8) with scaled pool row
    const float p = pool[b * CCH + tid] * (1.f / 3600.f);
    const float* w3r = w3 + (size_t)(c * 9) * CCH + tid;
    float part[9];
#pragma unroll
    for (int q = 0; q < 9; ++q) part[q] = w3r[(size_t)q * CCH] * p;
#pragma unroll
    for (int off = 32; off; off >>= 1)
#pragma unroll
        for (int q = 0; q < 9; ++q) part[q] += __shfl_down(part[q], off, 64);
    if (lane == 0) {
#pragma unroll
        for (int q = 0; q < 9; ++q) t[wv * 9 + q] = part[q];
    }
    __syncthreads();
    float k[9];
#pragma unroll
    for (int q = 0; q < 9; ++q)
        k[q] = t[q] + t[9 + q] + t[18 + q] + t[27 + q] + b3[c * 9 + q];
    __syncthreads();                                   // t[] reused below

    if (tid < 67) { t[tid] = 0.f; t[65 * 67 + tid] = 0.f; }          // rows 0, 65
    if (tid >= 128 && tid < 192) {
        int r = tid - 127;                                            // 1..64
        t[r * 67] = 0.f; t[r * 67 + 65] = 0.f;                        // cols 0, 65
    }

    const float bs = bias[c];
    const float* xp = x + (size_t)bc * 4096;
    float* op = out + (size_t)bc * 4096;
    __syncthreads();

#pragma unroll
    for (int i = 0; i < 4; ++i) {
        int p4 = tid + i * 256;            // float4 index 0..1023
        float4 v = *(const float4*)(xp + p4 * 4);
        int yy = p4 >> 4, xx = (p4 & 15) * 4;
        float* d = &t[(yy + 1) * 67 + 1 + xx];
        d[0] = v.x; d[1] = v.y; d[2] = v.z; d[3] = v.w;
    }
    __syncthreads();

#pragma unroll
    for (int i = 0; i < 4; ++i) {
        int p4 = tid + i * 256;
        int yy = p4 >> 4, xx = (p4 & 15) * 4;
        float r[3][6];
#pragma unroll
        for (int dy = 0; dy < 3; ++dy)
#pragma unroll
            for (int dx = 0; dx < 6; ++dx)
                r[dy][dx] = t[(yy + dy) * 67 + xx + dx];
        float4 o;
        float* ov = (float*)&o;
#pragma unroll
        for (int j = 0; j < 4; ++j) {
            float a = bs;
#pragma unroll
            for (int dy = 0; dy < 3; ++dy)
#pragma unroll
                for (int dx = 0; dx < 3; ++dx)
                    a += k[dy * 3 + dx] * r[dy][j + dx];
            ov[j] = a;
        }
        *(float4*)(op + p4 * 4) = o;
    }
}

extern "C" void kernel_launch(void* const* d_in, const int* in_sizes, int n_in,
                              void* d_out, int out_size, void* d_ws, size_t ws_size,
                              hipStream_t stream)
{
    const float* x    = (const float*)d_in[0];
    const float* kin  = (const float*)d_in[1];
    const float* w1   = (const float*)d_in[2];
    const float* b1   = (const float*)d_in[3];
    const float* w2   = (const float*)d_in[4];
    const float* b2   = (const float*)d_in[5];
    const float* w3   = (const float*)d_in[6];
    const float* b3   = (const float*)d_in[7];
    const float* bias = (const float*)d_in[8];

    // ws: imA [16][8][4096][32] bf16 | h1 [16][8][3844][32] bf16 (+slack) | w1t | w2t | pool
    unsigned short* imA = (unsigned short*)d_ws;
    unsigned short* h1  = imA + (size_t)16 * 8 * 4096 * 32;
    unsigned short* w1t = h1 + (size_t)16 * 8 * 3844 * 32 + 8192;   // slack for clamped-tap reads
    unsigned short* w2t = w1t + (size_t)72 * 8192;
    float* pool = (float*)(w2t + (size_t)72 * 8192);

    float* out = (float*)d_out;

    hipLaunchKernelGGL(pre_k, dim3(8, 64, 17), dim3(256), 0, stream,
                       kin, imA, w1, w2, w1t, w2t, pool);
    hipLaunchKernelGGL((convmm_k<0, 64, 62>), dim3(31, 16), dim3(256), 0, stream,
                       imA, w1t, b1, h1, (float*)nullptr);
    hipLaunchKernelGGL((convmm_k<1, 62, 60>), dim3(29, 16), dim3(256), 0, stream,
                       h1, w2t, b2, (unsigned short*)nullptr, pool);
    hipLaunchKernelGGL(dw_k, dim3(16 * 256), dim3(256), 0, stream,
                       x, pool, w3, b3, bias, out);
}